// Round 1
// baseline (1279.809 us; speedup 1.0000x reference)
//
#include <hip/hip_runtime.h>

typedef __bf16 bf16x8 __attribute__((ext_vector_type(8)));
typedef float  f32x4  __attribute__((ext_vector_type(4)));

#define NB 8
#define NC 64
#define NH 256
#define NW 256
#define LDSW 258   // w rows: pad row 0 (w=-1) and 257 (w=256), zeroed once
#define LDSC 72    // ci stride: 144 B rows -> ds_read_b128 2-way alias only

// tanh(x) = 1 - 2/(1+e^{2x}); bounded, branch-free, NaN-free for finite x
// (kept bit-identical to the previously passing kernel)
__device__ __forceinline__ float fast_tanh(float x) {
    float e = __expf(2.0f * x);
    return 1.0f - 2.0f / (1.0f + e);
}

// One WG per batch: the whole W=256 row lives in LDS, double-buffered.
// 8 waves; wave v owns w-tiles {2v, 2v+1} x all 4 co-tiles (8 MFMA tiles).
// MFMA roles: A = prev row (m=w, k=ci), B = weights (k=ci, n=co) so each
// lane's 4 outputs are 4 consecutive w at fixed co -> dwordx4 X/Y access.
// No inter-WG communication at all: no flags, no fences, no halo refill.
__global__ __launch_bounds__(512, 2)
void spconv_row(const float* __restrict__ Xg,
                const float* __restrict__ Wg,
                const float* __restrict__ Bg,
                float* __restrict__ Yg)
{
    const int b    = blockIdx.x;
    const int tid  = threadIdx.x;
    const int wv   = tid >> 6;       // 0..7
    const int lane = tid & 63;
    const int g    = lane >> 4;      // 0..3
    const int lm   = lane & 15;

    __shared__ __bf16 ybuf[2][LDSW][LDSC];   // 74.3 KB

    const float* Xb = Xg + (size_t)b * NC * NH * NW;
    float*       Yb = Yg + (size_t)b * NC * NH * NW;

    // ---- resident weights: wfrag[ct][c][j] = W[ct*16+lm][32*(c&1)+8g+j][c>>1]
    // (B-operand layout: n = lane&15 = co_local, k = (lane>>4)*8+j = ci chunk)
    bf16x8 wfrag[4][6];
    #pragma unroll
    for (int ct = 0; ct < 4; ++ct) {
        const int co = ct * 16 + lm;
        #pragma unroll
        for (int c = 0; c < 6; ++c) {
            const int tap = c >> 1, ci0 = 32 * (c & 1) + 8 * g;
            bf16x8 a;
            #pragma unroll
            for (int j = 0; j < 8; ++j)
                a[j] = (__bf16)Wg[(co * NC + ci0 + j) * 3 + tap];
            wfrag[ct][c] = a;
        }
    }
    float bias_r[4];
    #pragma unroll
    for (int ct = 0; ct < 4; ++ct)
        bias_r[ct] = Bg[ct * 16 + lm];

    // ---- zero the pad rows of BOTH buffers (rows 0 and 257) ----
    for (int i = tid; i < 2 * 2 * LDSC; i += 512) {
        const int bsel = i / (2 * LDSC);
        const int rem  = i % (2 * LDSC);
        const int r    = (rem / LDSC) ? (LDSW - 1) : 0;
        ybuf[bsel][r][rem % LDSC] = (__bf16)0.0f;
    }
    // ---- row 0: Y = X (fp32 passthrough) and LDS <- bf16(X row 0) ----
    {
        const int ci = tid >> 3;            // 64 channels
        const int w0 = (tid & 7) * 32;      // 32 w per thread
        #pragma unroll
        for (int k = 0; k < 8; ++k) {
            const int w = w0 + k * 4;
            const f32x4 v = *(const f32x4*)&Xb[(ci * NH + 0) * NW + w];
            *(f32x4*)&Yb[(ci * NH + 0) * NW + w] = v;
            #pragma unroll
            for (int j = 0; j < 4; ++j)
                ybuf[0][w + j + 1][ci] = (__bf16)v[j];
        }
    }

    // lane's w base for output rows: w = wbase + 16*t2 + i, i = 0..3 via 4g+i
    const int wbase = 32 * wv + 4 * g;

    // preload X row 1
    f32x4 xc[2][4];
    #pragma unroll
    for (int t2 = 0; t2 < 2; ++t2)
        #pragma unroll
        for (int ct = 0; ct < 4; ++ct)
            xc[t2][ct] = *(const f32x4*)
                &Xb[((ct * 16 + lm) * NH + 1) * NW + wbase + 16 * t2];

    __syncthreads();

    int p = 0;
    for (int h = 1; h < NH; ++h) {
        // ---- A-frags from prev row (lane: m = lm = w_local, k = ci chunk) ----
        bf16x8 afr[2][6];
        #pragma unroll
        for (int t2 = 0; t2 < 2; ++t2)
            #pragma unroll
            for (int c = 0; c < 6; ++c)
                afr[t2][c] = *(const bf16x8*)
                    &ybuf[p][32 * wv + 16 * t2 + lm + (c >> 1)]
                          [32 * (c & 1) + 8 * g];

        // ---- conv: acc chains over c = 0..5 (same order as before) ----
        f32x4 acc[2][4];
        #pragma unroll
        for (int t2 = 0; t2 < 2; ++t2)
            #pragma unroll
            for (int ct = 0; ct < 4; ++ct) {
                f32x4 a = {0.f, 0.f, 0.f, 0.f};
                #pragma unroll
                for (int c = 0; c < 6; ++c)
                    a = __builtin_amdgcn_mfma_f32_16x16x32_bf16(
                            afr[t2][c], wfrag[ct][c], a, 0, 0, 0);
                acc[t2][ct] = a;
            }

        // ---- epilogue: y = x + tanh(acc + bias); store Y; write LDS row ----
        #pragma unroll
        for (int t2 = 0; t2 < 2; ++t2)
            #pragma unroll
            for (int ct = 0; ct < 4; ++ct) {
                f32x4 y;
                #pragma unroll
                for (int i = 0; i < 4; ++i)
                    y[i] = xc[t2][ct][i] + fast_tanh(acc[t2][ct][i] + bias_r[ct]);
                *(f32x4*)&Yb[((ct * 16 + lm) * NH + h) * NW + wbase + 16 * t2] = y;
                const int row = wbase + 16 * t2 + 1;
                #pragma unroll
                for (int i = 0; i < 4; ++i)
                    ybuf[p ^ 1][row + i][ct * 16 + lm] = (__bf16)y[i];
            }

        // ---- prefetch X row h+1 (consumed next step's epilogue) ----
        if (h + 1 < NH) {
            #pragma unroll
            for (int t2 = 0; t2 < 2; ++t2)
                #pragma unroll
                for (int ct = 0; ct < 4; ++ct)
                    xc[t2][ct] = *(const f32x4*)
                        &Xb[((ct * 16 + lm) * NH + h + 1) * NW + wbase + 16 * t2];
        }

        // ---- LDS-only barrier: do NOT drain vmcnt (stores/prefetch float) ----
        asm volatile("s_waitcnt lgkmcnt(0)" ::: "memory");
        __builtin_amdgcn_sched_barrier(0);
        __builtin_amdgcn_s_barrier();
        __builtin_amdgcn_sched_barrier(0);
        p ^= 1;
    }
}

extern "C" void kernel_launch(void* const* d_in, const int* in_sizes, int n_in,
                              void* d_out, int out_size, void* d_ws, size_t ws_size,
                              hipStream_t stream)
{
    const float* X  = (const float*)d_in[0];
    const float* Wc = (const float*)d_in[1];
    const float* Bc = (const float*)d_in[2];
    float* Y        = (float*)d_out;

    dim3 grid(NB);      // one WG per batch; no inter-WG deps, no workspace
    dim3 block(512);    // 8 waves = 2/SIMD
    hipLaunchKernelGGL(spconv_row, grid, block, 0, stream, X, Wc, Bc, Y);
}

// Round 2
// 817.685 us; speedup vs baseline: 1.5652x; 1.5652x over previous
//
#include <hip/hip_runtime.h>

typedef __bf16 bf16x8 __attribute__((ext_vector_type(8)));
typedef __bf16 bf16x4 __attribute__((ext_vector_type(4)));
typedef float  f32x4  __attribute__((ext_vector_type(4)));

#define NB 8
#define NC 64
#define NH 256
#define NW 256
#define NT 16     // W tiles
#define WT 16     // core width per WG
#define SEG 16    // steps between neighbor syncs
#define CW 48     // computed window width (core + 16 halo each side)
#define LDSW 50   // window + conv pad columns, w = wc0-1 .. wc0+48
#define LDSC 72   // ci stride: 144 B rows keep ds_read_b128 16B-aligned

// tanh(x) = 1 - 2/(1+e^{2x}); bounded, branch-free, NaN-free for finite x
__device__ __forceinline__ float fast_tanh(float x) {
    float e = __expf(2.0f * x);
    return 1.0f - 2.0f / (1.0f + e);
}

// 128 WGs = 8 batches x 16 W-tiles; blockIdx&7 = batch -> same-batch tiles
// share an XCD (perf heuristic only; agent-scope sync gives correctness).
// Each WG computes a 48-wide trapezoid window; neighbor halo exchange through
// global Y only every SEG steps.
//
// vs the 648us version: (1) window LDS is double-buffered -> ONE barrier per
// step instead of two; (2) that barrier is lgkmcnt-only (raw s_barrier), so
// X prefetch loads and Y store acks are NOT drained per step (vmcnt drains
// only at segment boundaries via __threadfence); (3) h-loop unrolled x2 with
// ping-pong prefetch registers -> no xcur=xnext copy forcing vmcnt(0) at
// step end, and buffer parity is compile-time.
__global__ __launch_bounds__(256, 1)
void spconv_trap(const float* __restrict__ Xg,
                 const float* __restrict__ Wg,
                 const float* __restrict__ Bg,
                 float* __restrict__ Yg,
                 int* __restrict__ flags)
{
    const int b    = blockIdx.x & 7;
    const int t    = blockIdx.x >> 3;
    const int tid  = threadIdx.x;
    const int wv   = tid >> 6;     // 0..3: wave = co-tile
    const int lane = tid & 63;
    const int g    = lane >> 4;    // quad
    const int lm   = lane & 15;
    const int w0   = t * WT;
    const int wc0  = w0 - WT;      // window start

    __shared__ __bf16 buf[2][LDSW][LDSC];  // double-buffered prev row, 14.4 KB

    // ---- A fragments (this wave's co-tile only), resident in VGPRs ----
    // chunk c: k-tap = c>>1, ci0 = 32*(c&1)+8g; A[m=lm][q=8g+j]=W[co][ci0+j][k]
    bf16x8 afrag[6];
    {
        const int co = wv * 16 + lm;
        #pragma unroll
        for (int c = 0; c < 6; ++c) {
            const int k = c >> 1, ci0 = 32 * (c & 1) + 8 * g;
            bf16x8 a;
            #pragma unroll
            for (int j = 0; j < 8; ++j)
                a[j] = (__bf16)Wg[(co * NC + ci0 + j) * 3 + k];
            afrag[c] = a;
        }
    }
    float bias_r[4];
    #pragma unroll
    for (int i = 0; i < 4; ++i)
        bias_r[i] = Bg[wv * 16 + 4 * g + i];

    // ---- init: BOTH buffers <- X row 0 over the window (clamped outside) ----
    // (rows 0 and LDSW-1 are only ever written here; they feed margin cells
    // whose garbage never reaches the core between boundary refills)
    {
        const int ci = tid & 63;
        for (int r = (tid >> 6); r < LDSW; r += 4) {
            const int w = wc0 - 1 + r;
            float v = (w >= 0 && w < NW)
                    ? Xg[((size_t)(b * NC + ci) * NH + 0) * NW + w] : 0.0f;
            const __bf16 bv = (__bf16)v;
            buf[0][r][ci] = bv;
            buf[1][r][ci] = bv;
        }
    }
    // Y row 0 = X row 0 (exact fp32 passthrough), core columns only
    #pragma unroll
    for (int i = 0; i < 4; ++i) {
        const int co = wv * 16 + 4 * g + i;
        const size_t idx = ((size_t)(b * NC + co) * NH + 0) * NW + w0 + lm;
        Yg[idx] = Xg[idx];
    }

    // per-lane window columns and validity (fixed for the whole kernel)
    bool wok[3];
    #pragma unroll
    for (int s = 0; s < 3; ++s) {
        const int w = wc0 + 16 * s + lm;
        wok[s] = (w >= 0 && w < NW);
    }

    // ping-pong X prefetch registers; preload row 1 into xA
    float xA[3][4], xB[3][4];
    #pragma unroll
    for (int s = 0; s < 3; ++s)
        #pragma unroll
        for (int i = 0; i < 4; ++i) {
            const int co = wv * 16 + 4 * g + i;
            const int w  = wc0 + 16 * s + lm;
            xA[s][i] = wok[s]
                ? Xg[((size_t)(b * NC + co) * NH + 1) * NW + w] : 0.0f;
        }
    __syncthreads();

    const int myflag = b * NT + t;

    // p is a compile-time constant at each call site (body inlined twice per
    // unrolled pair), so all LDS bases fold to immediates.
    auto body = [&](int h, int p, float (&xcur)[3][4], float (&xnext)[3][4]) {
        // ---- prefetch X[h+1] at step top: ~1 full step to cover HBM ----
        if (h + 1 < NH) {
            #pragma unroll
            for (int s = 0; s < 3; ++s)
                #pragma unroll
                for (int i = 0; i < 4; ++i) {
                    const int co = wv * 16 + 4 * g + i;
                    const int w  = wc0 + 16 * s + lm;
                    xnext[s][i] = wok[s]
                        ? Xg[((size_t)(b * NC + co) * NH + h + 1) * NW + w] : 0.0f;
                }
        }

        // ---- conv over 3 w-subtiles from buf[p]: D = sum_c A_c*B_c, K=192 ----
        float yv[3][4];
        #pragma unroll
        for (int s = 0; s < 3; ++s) {
            f32x4 acc = {0.f, 0.f, 0.f, 0.f};
            #pragma unroll
            for (int c = 0; c < 6; ++c) {
                const bf16x8 bfr =
                    *(const bf16x8*)&buf[p][16 * s + lm + (c >> 1)][32 * (c & 1) + 8 * g];
                acc = __builtin_amdgcn_mfma_f32_16x16x32_bf16(afrag[c], bfr, acc, 0, 0, 0);
            }
            #pragma unroll
            for (int i = 0; i < 4; ++i)
                yv[s][i] = xcur[s][i] + fast_tanh(acc[i] + bias_r[i]);
        }
        // ---- store core columns (s = 1) to global, fp32 (acks NOT drained) ----
        #pragma unroll
        for (int i = 0; i < 4; ++i) {
            const int co = wv * 16 + 4 * g + i;
            Yg[((size_t)(b * NC + co) * NH + h) * NW + w0 + lm] = yv[1][i];
        }

        // ---- write new row into the OTHER buffer (no read-WAR barrier) ----
        #pragma unroll
        for (int s = 0; s < 3; ++s) {
            bf16x4 pk;
            #pragma unroll
            for (int i = 0; i < 4; ++i)
                pk[i] = wok[s] ? (__bf16)yv[s][i] : (__bf16)0.0f;
            *(bf16x4*)&buf[p ^ 1][16 * s + lm + 1][wv * 16 + 4 * g] = pk;
        }

        const bool boundary = (h < NH - 1) && ((h & (SEG - 1)) == 0);
        if (boundary) {
            const int k = h >> 4;          // completed segment index, 1..15
            __threadfence();               // publish my Y stores (drains vmcnt)
            __syncthreads();               // all fences done before flag store
            if (tid == 0)
                __hip_atomic_store(&flags[myflag], k,
                                   __ATOMIC_RELEASE, __HIP_MEMORY_SCOPE_AGENT);
            // spin in two different waves so the waits overlap
            if (t > 0 && tid == 32) {
                while (__hip_atomic_load(&flags[myflag - 1], __ATOMIC_ACQUIRE,
                                         __HIP_MEMORY_SCOPE_AGENT) < k)
                    __builtin_amdgcn_s_sleep(2);
            }
            if (t < NT - 1 && tid == 96) {
                while (__hip_atomic_load(&flags[myflag + 1], __ATOMIC_ACQUIRE,
                                         __HIP_MEMORY_SCOPE_AGENT) < k)
                    __builtin_amdgcn_s_sleep(2);
            }
            __syncthreads();
            // refill halo regions of buf[p^1] from neighbors' Y[h]
            for (int idx = tid; idx < 2048; idx += 256) {
                const int wloc = idx & 15;
                const int ci   = (idx >> 4) & 63;
                const int side = idx >> 10;            // 0 = left, 1 = right
                const bool have = side ? (t < NT - 1) : (t > 0);
                if (have) {
                    const int w = w0 - 16 + wloc + side * 32;
                    const int r = side * 32 + wloc + 1;
                    buf[p ^ 1][r][ci] =
                        (__bf16)Yg[((size_t)(b * NC + ci) * NH + h) * NW + w];
                }
            }
            __syncthreads();
        } else {
            // LDS-only barrier: new-row ds_writes visible, vmcnt NOT drained
            asm volatile("s_waitcnt lgkmcnt(0)" ::: "memory");
            __builtin_amdgcn_sched_barrier(0);
            __builtin_amdgcn_s_barrier();
            __builtin_amdgcn_sched_barrier(0);
        }
    };

    // h odd -> reads buf[0], writes buf[1]; h even -> the reverse.
    // Boundaries (h % 16 == 0) always land in the second body (p = 1).
    for (int h = 1; h < NH; h += 2) {
        body(h, 0, xA, xB);
        if (h + 1 < NH) body(h + 1, 1, xB, xA);
    }
}

extern "C" void kernel_launch(void* const* d_in, const int* in_sizes, int n_in,
                              void* d_out, int out_size, void* d_ws, size_t ws_size,
                              hipStream_t stream)
{
    const float* X  = (const float*)d_in[0];
    const float* Wc = (const float*)d_in[1];
    const float* Bc = (const float*)d_in[2];
    float* Y        = (float*)d_out;
    int* flags      = (int*)d_ws;   // 128 ints; d_ws is poisoned 0xAA -> memset

    hipMemsetAsync(d_ws, 0, NB * NT * sizeof(int), stream);

    dim3 grid(NB * NT);   // 128 WGs x 4 waves: all co-resident, spin-safe
    dim3 block(256);
    hipLaunchKernelGGL(spconv_trap, grid, block, 0, stream, X, Wc, Bc, Y, flags);
}

// Round 3
// 728.027 us; speedup vs baseline: 1.7579x; 1.1232x over previous
//
#include <hip/hip_runtime.h>

typedef __bf16 bf16x8 __attribute__((ext_vector_type(8)));
typedef __bf16 bf16x4 __attribute__((ext_vector_type(4)));
typedef float  f32x4  __attribute__((ext_vector_type(4)));

#define NB 8
#define NC 64
#define NH 256
#define NW 256
#define NT 16     // W tiles
#define WT 16     // core width per WG
#define SEG 32    // steps between neighbor syncs == halo width per side
#define NS 5      // window subtiles: (WT + 2*SEG)/16
#define LDSW 82   // window + conv pad columns, w = wc0-1 .. wc0+80
#define LDSC 72   // ci stride: 144 B rows keep ds_read_b128 16B-aligned

// tanh(x) = 1 - 2/(1+e^{2x}); bounded, branch-free, NaN-free for finite x
__device__ __forceinline__ float fast_tanh(float x) {
    float e = __expf(2.0f * x);
    return 1.0f - 2.0f / (1.0f + e);
}

// 128 WGs = 8 batches x 16 W-tiles; blockIdx&7 = batch -> same-batch tiles
// share an XCD. Each WG computes an 80-wide trapezoid window (16 core +
// 32 halo each side); neighbor halo exchange through global Y every SEG=32
// steps (7 boundaries instead of 15 at SEG=16). Halo validity erodes one
// column per side per step, so after 32 steps exactly the 16-wide core is
// still exact -- same invariant as the verified SEG=16 kernel, numerics
// bitwise identical (same MFMA order, same tanh, same bf16 rounding).
__global__ __launch_bounds__(256, 1)
void spconv_trap(const float* __restrict__ Xg,
                 const float* __restrict__ Wg,
                 const float* __restrict__ Bg,
                 float* __restrict__ Yg,
                 int* __restrict__ flags)
{
    const int b    = blockIdx.x & 7;
    const int t    = blockIdx.x >> 3;
    const int tid  = threadIdx.x;
    const int wv   = tid >> 6;     // 0..3: wave = co-tile
    const int lane = tid & 63;
    const int g    = lane >> 4;    // quad
    const int lm   = lane & 15;
    const int w0   = t * WT;
    const int wc0  = w0 - SEG;     // window start

    __shared__ __bf16 buf[2][LDSW][LDSC];  // double-buffered prev row, 23.6 KB

    // ---- A fragments (this wave's co-tile only), resident in VGPRs ----
    // chunk c: k-tap = c>>1, ci0 = 32*(c&1)+8g; A[m=lm][q=8g+j]=W[co][ci0+j][k]
    bf16x8 afrag[6];
    {
        const int co = wv * 16 + lm;
        #pragma unroll
        for (int c = 0; c < 6; ++c) {
            const int k = c >> 1, ci0 = 32 * (c & 1) + 8 * g;
            bf16x8 a;
            #pragma unroll
            for (int j = 0; j < 8; ++j)
                a[j] = (__bf16)Wg[(co * NC + ci0 + j) * 3 + k];
            afrag[c] = a;
        }
    }
    float bias_r[4];
    #pragma unroll
    for (int i = 0; i < 4; ++i)
        bias_r[i] = Bg[wv * 16 + 4 * g + i];

    // ---- init: BOTH buffers <- X row 0 over the window (clamped outside) ----
    {
        const int ci = tid & 63;
        for (int r = (tid >> 6); r < LDSW; r += 4) {
            const int w = wc0 - 1 + r;
            float v = (w >= 0 && w < NW)
                    ? Xg[((size_t)(b * NC + ci) * NH + 0) * NW + w] : 0.0f;
            const __bf16 bv = (__bf16)v;
            buf[0][r][ci] = bv;
            buf[1][r][ci] = bv;
        }
    }
    // Y row 0 = X row 0 (exact fp32 passthrough), core columns only
    #pragma unroll
    for (int i = 0; i < 4; ++i) {
        const int co = wv * 16 + 4 * g + i;
        const size_t idx = ((size_t)(b * NC + co) * NH + 0) * NW + w0 + lm;
        Yg[idx] = Xg[idx];
    }

    // per-lane window columns and validity (fixed for the whole kernel)
    bool wok[NS];
    #pragma unroll
    for (int s = 0; s < NS; ++s) {
        const int w = wc0 + 16 * s + lm;
        wok[s] = (w >= 0 && w < NW);
    }

    // ping-pong X prefetch registers; preload row 1 into xA
    float xA[NS][4], xB[NS][4];
    #pragma unroll
    for (int s = 0; s < NS; ++s)
        #pragma unroll
        for (int i = 0; i < 4; ++i) {
            const int co = wv * 16 + 4 * g + i;
            const int w  = wc0 + 16 * s + lm;
            xA[s][i] = wok[s]
                ? Xg[((size_t)(b * NC + co) * NH + 1) * NW + w] : 0.0f;
        }
    __syncthreads();

    const int myflag = b * NT + t;

    // p is a compile-time constant at each call site (body inlined twice per
    // unrolled pair), so all LDS bases fold to immediates.
    auto body = [&](int h, int p, float (&xcur)[NS][4], float (&xnext)[NS][4]) {
        // ---- prefetch X[h+1] at step top: ~1 full step to cover HBM ----
        if (h + 1 < NH) {
            #pragma unroll
            for (int s = 0; s < NS; ++s)
                #pragma unroll
                for (int i = 0; i < 4; ++i) {
                    const int co = wv * 16 + 4 * g + i;
                    const int w  = wc0 + 16 * s + lm;
                    xnext[s][i] = wok[s]
                        ? Xg[((size_t)(b * NC + co) * NH + h + 1) * NW + w] : 0.0f;
                }
        }

        // ---- conv over NS w-subtiles from buf[p]: D = sum_c A_c*B_c, K=192 ----
        float yv[NS][4];
        #pragma unroll
        for (int s = 0; s < NS; ++s) {
            f32x4 acc = {0.f, 0.f, 0.f, 0.f};
            #pragma unroll
            for (int c = 0; c < 6; ++c) {
                const bf16x8 bfr =
                    *(const bf16x8*)&buf[p][16 * s + lm + (c >> 1)][32 * (c & 1) + 8 * g];
                acc = __builtin_amdgcn_mfma_f32_16x16x32_bf16(afrag[c], bfr, acc, 0, 0, 0);
            }
            #pragma unroll
            for (int i = 0; i < 4; ++i)
                yv[s][i] = xcur[s][i] + fast_tanh(acc[i] + bias_r[i]);
        }
        // ---- store core columns (subtile SEG/16 = 2) to global, fp32 ----
        #pragma unroll
        for (int i = 0; i < 4; ++i) {
            const int co = wv * 16 + 4 * g + i;
            Yg[((size_t)(b * NC + co) * NH + h) * NW + w0 + lm] = yv[SEG / 16][i];
        }

        // ---- write new row into the OTHER buffer (no read-WAR barrier) ----
        #pragma unroll
        for (int s = 0; s < NS; ++s) {
            bf16x4 pk;
            #pragma unroll
            for (int i = 0; i < 4; ++i)
                pk[i] = wok[s] ? (__bf16)yv[s][i] : (__bf16)0.0f;
            *(bf16x4*)&buf[p ^ 1][16 * s + lm + 1][wv * 16 + 4 * g] = pk;
        }

        const bool boundary = (h < NH - 1) && ((h & (SEG - 1)) == 0);
        if (boundary) {
            const int k = h >> 5;          // completed segment index, 1..7
            __threadfence();               // publish my Y stores (drains vmcnt)
            __syncthreads();               // all fences done before flag store
            if (tid == 0)
                __hip_atomic_store(&flags[myflag], k,
                                   __ATOMIC_RELEASE, __HIP_MEMORY_SCOPE_AGENT);
            // spin in two different waves so the waits overlap
            if (t > 0 && tid == 32) {
                while (__hip_atomic_load(&flags[myflag - 1], __ATOMIC_ACQUIRE,
                                         __HIP_MEMORY_SCOPE_AGENT) < k)
                    __builtin_amdgcn_s_sleep(2);
            }
            if (t < NT - 1 && tid == 96) {
                while (__hip_atomic_load(&flags[myflag + 1], __ATOMIC_ACQUIRE,
                                         __HIP_MEMORY_SCOPE_AGENT) < k)
                    __builtin_amdgcn_s_sleep(2);
            }
            __syncthreads();
            // refill halo regions of buf[p^1] from neighbors' Y[h]
            // left: rows 1..32 (w = w0-32..w0-1); right: rows 49..80
            for (int idx = tid; idx < 2 * SEG * NC; idx += 256) {
                const int wloc = idx & 31;
                const int ci   = (idx >> 5) & 63;
                const int side = idx >> 11;            // 0 = left, 1 = right
                const bool have = side ? (t < NT - 1) : (t > 0);
                if (have) {
                    const int w = w0 - SEG + wloc + side * (WT + SEG);
                    const int r = wloc + 1 + side * (WT + SEG);
                    buf[p ^ 1][r][ci] =
                        (__bf16)Yg[((size_t)(b * NC + ci) * NH + h) * NW + w];
                }
            }
            __syncthreads();
        } else {
            // LDS-only barrier: new-row ds_writes visible, vmcnt NOT drained
            asm volatile("s_waitcnt lgkmcnt(0)" ::: "memory");
            __builtin_amdgcn_sched_barrier(0);
            __builtin_amdgcn_s_barrier();
            __builtin_amdgcn_sched_barrier(0);
        }
    };

    // h odd -> reads buf[0], writes buf[1]; h even -> the reverse.
    // Boundaries (h % 32 == 0) always land in the second body (p = 1).
    for (int h = 1; h < NH; h += 2) {
        body(h, 0, xA, xB);
        if (h + 1 < NH) body(h + 1, 1, xB, xA);
    }
}

extern "C" void kernel_launch(void* const* d_in, const int* in_sizes, int n_in,
                              void* d_out, int out_size, void* d_ws, size_t ws_size,
                              hipStream_t stream)
{
    const float* X  = (const float*)d_in[0];
    const float* Wc = (const float*)d_in[1];
    const float* Bc = (const float*)d_in[2];
    float* Y        = (float*)d_out;
    int* flags      = (int*)d_ws;   // 128 ints; d_ws is poisoned 0xAA -> memset

    hipMemsetAsync(d_ws, 0, NB * NT * sizeof(int), stream);

    dim3 grid(NB * NT);   // 128 WGs x 4 waves: all co-resident, spin-safe
    dim3 block(256);
    hipLaunchKernelGGL(spconv_trap, grid, block, 0, stream, X, Wc, Bc, Y, flags);
}